// Round 1
// 454.374 us; speedup vs baseline: 1.1251x; 1.1251x over previous
//
#include <hip/hip_runtime.h>
#include <hip/hip_fp16.h>

#define N_NODES 100000
#define N_EDGES 3200000
#define F_IN    512
#define HID     16
#define NCLS    10
#define NB      196        // ceil(100000/512) buckets of 512 nodes
#define EPB     4096       // edges per block in k_bpart
#define TK      32         // gemm1 K-chunk

// ---- fp16 pack/unpack helpers (register-safe: no pointer reinterpret of arrays)
union H2F { __half2 h; float f; };
__device__ __forceinline__ float h2f_pack(float a, float b) {
    H2F u; u.h = __floats2half2_rn(a, b); return u.f;
}
__device__ __forceinline__ void h2f_add(float raw, float& a, float& b) {
    H2F u; u.f = raw; float2 v = __half22float2(u.h); a += v.x; b += v.y;
}
__device__ __forceinline__ void acc4(float2 raw, float& a, float& b, float& c, float& d) {
    h2f_add(raw.x, a, b); h2f_add(raw.y, c, d);
}

// ---------------- zero the padded bucket counters (re-poisoned every call)
__global__ __launch_bounds__(256) void k_binit(int* __restrict__ bcntp) {
    int i = blockIdx.x * 256 + threadIdx.x;
    if (i < NB * 16) bcntp[i] = 0;
}

// ---------------- bucket histogram via LDS (196 buckets, dst>>9)
__global__ __launch_bounds__(256) void k_bhist(const int* __restrict__ dst,
                                               int* __restrict__ bcntp) {
    __shared__ int h[256];
    int t = threadIdx.x;
    h[t] = 0;
    __syncthreads();
    int hi = min(N_EDGES, (int)(blockIdx.x + 1) * 8192);
    for (int e = blockIdx.x * 8192 + t; e < hi; e += 256)
        atomicAdd(&h[dst[e] >> 9], 1);
    __syncthreads();
    if (t < NB) {
        int v = h[t];
        if (v) atomicAdd(&bcntp[t * 16], v);   // padded: 1 counter per 64B line
    }
}

// ---------------- scan bucket counts -> boff[NB+1], init padded cursors
__global__ __launch_bounds__(256) void k_bscan(const int* __restrict__ bcntp,
                                               int* __restrict__ boff,
                                               int* __restrict__ bcurp,
                                               int* __restrict__ row) {
    __shared__ int sh[256];
    int t = threadIdx.x;
    int v = (t < NB) ? bcntp[t * 16] : 0;
    sh[t] = v;
    __syncthreads();
    for (int off = 1; off < 256; off <<= 1) {
        int add = (t >= off) ? sh[t - off] : 0;
        __syncthreads();
        sh[t] += add;
        __syncthreads();
    }
    int excl = sh[t] - v;
    if (t < NB) { boff[t] = excl; bcurp[t * 16] = excl; }
    if (t == 0) { boff[NB] = N_EDGES; row[N_NODES] = N_EDGES; }
}

// ---------------- multisplit partition: edges -> bucket-contiguous packed array
// packed word: ((d & 511) << 17) | s   (s < 2^17, local d < 2^9)
__global__ __launch_bounds__(256) void k_bpart(const int* __restrict__ ei,
                                               int* __restrict__ bcurp,
                                               int* __restrict__ part) {
    __shared__ int cnt_sh[256], base_sh[256];
    int t = threadIdx.x;
    cnt_sh[t] = 0;
    __syncthreads();
    int base = blockIdx.x * EPB;
    int pk[16], bk[16], rk[16];
#pragma unroll
    for (int j = 0; j < 16; ++j) {
        int e = base + j * 256 + t;
        if (e < N_EDGES) {
            int s = ei[e], d = ei[N_EDGES + e];
            bk[j] = d >> 9;
            pk[j] = ((d & 511) << 17) | s;
            rk[j] = atomicAdd(&cnt_sh[bk[j]], 1);
        } else bk[j] = -1;
    }
    __syncthreads();
    if (t < NB && cnt_sh[t] > 0)
        base_sh[t] = atomicAdd(&bcurp[t * 16], cnt_sh[t]);
    __syncthreads();
#pragma unroll
    for (int j = 0; j < 16; ++j)
        if (bk[j] >= 0) part[base_sh[bk[j]] + rk[j]] = pk[j];
}

// ---------------- per-bucket: node counts, scan, row/dinv, place srcs (all LDS)
// 196 blocks -> 1 wave/SIMD: both edge passes 4-way unrolled for MLP.
__global__ __launch_bounds__(256) void k_bucket(const int* __restrict__ boff,
                                                const int* __restrict__ part,
                                                int* __restrict__ row,
                                                float* __restrict__ dinv,
                                                int* __restrict__ srcs) {
    __shared__ int cnt[512], ofs[512], sc[256];
    int t = threadIdx.x;
    int b = blockIdx.x;
    int e0 = boff[b], e1 = boff[b + 1];
    int nbase = b << 9;
    cnt[t] = 0; cnt[t + 256] = 0;
    __syncthreads();
    for (int e = e0 + t; e < e1; e += 1024) {
        int p0 = part[e];
        int p1 = (e + 256 < e1) ? part[e + 256] : -1;
        int p2 = (e + 512 < e1) ? part[e + 512] : -1;
        int p3 = (e + 768 < e1) ? part[e + 768] : -1;
        atomicAdd(&cnt[p0 >> 17], 1);
        if (p1 >= 0) atomicAdd(&cnt[p1 >> 17], 1);
        if (p2 >= 0) atomicAdd(&cnt[p2 >> 17], 1);
        if (p3 >= 0) atomicAdd(&cnt[p3 >> 17], 1);
    }
    __syncthreads();
    int a0 = cnt[2 * t], a1 = cnt[2 * t + 1];
    sc[t] = a0 + a1;
    __syncthreads();
    for (int off = 1; off < 256; off <<= 1) {
        int add = (t >= off) ? sc[t - off] : 0;
        __syncthreads();
        sc[t] += add;
        __syncthreads();
    }
    int excl = sc[t] - (a0 + a1);
    ofs[2 * t] = excl;
    ofs[2 * t + 1] = excl + a0;
    __syncthreads();
#pragma unroll
    for (int r = 0; r < 2; ++r) {
        int ln = t + r * 256;
        int n = nbase + ln;
        if (n < N_NODES) {
            row[n] = e0 + ofs[ln];
            dinv[n] = rsqrtf((float)(cnt[ln] + 1));   // +1 self-loop
        }
    }
    __syncthreads();
    for (int e = e0 + t; e < e1; e += 1024) {
        int p0 = part[e];
        int p1 = (e + 256 < e1) ? part[e + 256] : -1;
        int p2 = (e + 512 < e1) ? part[e + 512] : -1;
        int p3 = (e + 768 < e1) ? part[e + 768] : -1;
        int o0 = atomicAdd(&ofs[p0 >> 17], 1);
        srcs[e0 + o0] = p0 & 0x1FFFF;
        if (p1 >= 0) { int o = atomicAdd(&ofs[p1 >> 17], 1); srcs[e0 + o] = p1 & 0x1FFFF; }
        if (p2 >= 0) { int o = atomicAdd(&ofs[p2 >> 17], 1); srcs[e0 + o] = p2 & 0x1FFFF; }
        if (p3 >= 0) { int o = atomicAdd(&ofs[p3 >> 17], 1); srcs[e0 + o] = p3 & 0x1FFFF; }
    }
}

// ---------------- h1h = fp16( dinv[n] * (x @ W1) )   [32B/node row]
__global__ __launch_bounds__(128) void k_gemm1(const float* __restrict__ x,
                                               const float* __restrict__ W1,
                                               const float* __restrict__ dinv,
                                               __half* __restrict__ h1h) {
    __shared__ float xs[128][TK + 1];
    __shared__ float wchunk[TK * 16];      // 512 floats = 128 float4
    const int t = threadIdx.x;
    const int nbase = blockIdx.x * 128;
    const int f4 = t & 7;       // float4 index within chunk row (8 per row)
    const int r0 = t >> 3;      // 0..15; rows r0 + 16p

    float4 pre[8];
#pragma unroll
    for (int p = 0; p < 8; ++p) {
        int n = nbase + r0 + p * 16;
        pre[p] = (n < N_NODES) ? ((const float4*)(x + (size_t)n * F_IN))[f4]
                               : make_float4(0.f, 0.f, 0.f, 0.f);
    }
    float4 wpre = ((const float4*)W1)[t];   // chunk 0's W rows (32x16 = 128 f4)

    float acc[16];
#pragma unroll
    for (int j = 0; j < 16; ++j) acc[j] = 0.f;

    for (int c = 0; c < F_IN; c += TK) {
#pragma unroll
        for (int p = 0; p < 8; ++p) {
            int r = r0 + p * 16;
            xs[r][f4 * 4 + 0] = pre[p].x;
            xs[r][f4 * 4 + 1] = pre[p].y;
            xs[r][f4 * 4 + 2] = pre[p].z;
            xs[r][f4 * 4 + 3] = pre[p].w;
        }
        ((float4*)wchunk)[t] = wpre;
        __syncthreads();
        if (c + TK < F_IN) {
#pragma unroll
            for (int p = 0; p < 8; ++p) {
                int n = nbase + r0 + p * 16;
                pre[p] = (n < N_NODES)
                           ? ((const float4*)(x + (size_t)n * F_IN + c + TK))[f4]
                           : make_float4(0.f, 0.f, 0.f, 0.f);
            }
            wpre = ((const float4*)(W1 + (c + TK) * 16))[t];
        }
#pragma unroll
        for (int k = 0; k < TK; ++k) {
            float xv = xs[t][k];
            const float4* wk = (const float4*)&wchunk[k * 16];
            float4 wa = wk[0], wb = wk[1], wc = wk[2], wd = wk[3];
            acc[0]  = fmaf(xv, wa.x, acc[0]);
            acc[1]  = fmaf(xv, wa.y, acc[1]);
            acc[2]  = fmaf(xv, wa.z, acc[2]);
            acc[3]  = fmaf(xv, wa.w, acc[3]);
            acc[4]  = fmaf(xv, wb.x, acc[4]);
            acc[5]  = fmaf(xv, wb.y, acc[5]);
            acc[6]  = fmaf(xv, wb.z, acc[6]);
            acc[7]  = fmaf(xv, wb.w, acc[7]);
            acc[8]  = fmaf(xv, wc.x, acc[8]);
            acc[9]  = fmaf(xv, wc.y, acc[9]);
            acc[10] = fmaf(xv, wc.z, acc[10]);
            acc[11] = fmaf(xv, wc.w, acc[11]);
            acc[12] = fmaf(xv, wd.x, acc[12]);
            acc[13] = fmaf(xv, wd.y, acc[13]);
            acc[14] = fmaf(xv, wd.z, acc[14]);
            acc[15] = fmaf(xv, wd.w, acc[15]);
        }
        __syncthreads();
    }

    int n = nbase + t;
    if (n < N_NODES) {
        float dn = dinv[n];
        float4 o0 = make_float4(h2f_pack(acc[0]  * dn, acc[1]  * dn),
                                h2f_pack(acc[2]  * dn, acc[3]  * dn),
                                h2f_pack(acc[4]  * dn, acc[5]  * dn),
                                h2f_pack(acc[6]  * dn, acc[7]  * dn));
        float4 o1 = make_float4(h2f_pack(acc[8]  * dn, acc[9]  * dn),
                                h2f_pack(acc[10] * dn, acc[11] * dn),
                                h2f_pack(acc[12] * dn, acc[13] * dn),
                                h2f_pack(acc[14] * dn, acc[15] * dn));
        float4* o = (float4*)(h1h + (size_t)n * 16);
        o[0] = o0; o[1] = o1;
    }
}

// ---------------- layer-1 aggregate + fused gemm2 -> fp16 ps (16 halves/row).
// quad-per-node: lane q gathers the q-th 8B chunk of each fp16 neighbor row.
// Epilogue: relu -> partial @W2 (rows 4q..4q+3, W2 in LDS) -> quad xor-reduce
// -> dinv scale -> fp16 write (lane q writes ps cols 4q..4q+3; 10..15 zero).
__global__ __launch_bounds__(256) void k_edge1f(const int* __restrict__ row,
                                                const int* __restrict__ srcs,
                                                const float* __restrict__ dinv,
                                                const __half* __restrict__ h1h,
                                                const float* __restrict__ b1,
                                                const float* __restrict__ W2,
                                                __half* __restrict__ ps) {
    __shared__ float w2s[HID * NCLS];      // 160 floats
    if (threadIdx.x < HID * NCLS) w2s[threadIdx.x] = W2[threadIdx.x];
    __syncthreads();
    int t = blockIdx.x * 256 + threadIdx.x;
    if (t >= N_NODES * 4) return;
    int n = t >> 2, q = t & 3;
    const float2* h2 = (const float2*)h1h;
    float s0 = 0.f, s1 = 0.f, s2 = 0.f, s3 = 0.f;
    acc4(h2[n * 4 + q], s0, s1, s2, s3);          // self-loop (pre-scaled)
    int k = row[n], k1 = row[n + 1];
    for (; k + 8 <= k1; k += 8) {
        int a0 = srcs[k],     a1 = srcs[k + 1], a2 = srcs[k + 2], a3 = srcs[k + 3];
        int a4 = srcs[k + 4], a5 = srcs[k + 5], a6 = srcs[k + 6], a7 = srcs[k + 7];
        float2 v0 = h2[a0 * 4 + q], v1 = h2[a1 * 4 + q];
        float2 v2 = h2[a2 * 4 + q], v3 = h2[a3 * 4 + q];
        float2 v4 = h2[a4 * 4 + q], v5 = h2[a5 * 4 + q];
        float2 v6 = h2[a6 * 4 + q], v7 = h2[a7 * 4 + q];
        acc4(v0, s0, s1, s2, s3); acc4(v1, s0, s1, s2, s3);
        acc4(v2, s0, s1, s2, s3); acc4(v3, s0, s1, s2, s3);
        acc4(v4, s0, s1, s2, s3); acc4(v5, s0, s1, s2, s3);
        acc4(v6, s0, s1, s2, s3); acc4(v7, s0, s1, s2, s3);
    }
    if (k < k1) {                                  // masked 8-wide tail
        int sb = srcs[k];
        int idx[8]; float2 vv[8];
#pragma unroll
        for (int j = 0; j < 8; ++j) idx[j] = (k + j < k1) ? srcs[k + j] : sb;
#pragma unroll
        for (int j = 0; j < 8; ++j) vv[j] = h2[idx[j] * 4 + q];
#pragma unroll
        for (int j = 0; j < 8; ++j)
            if (k + j < k1) acc4(vv[j], s0, s1, s2, s3);
    }
    float dn = dinv[n];
    int c0 = q * 4;
    float r0 = fmaxf(fmaf(dn, s0, b1[c0 + 0]), 0.f);
    float r1 = fmaxf(fmaf(dn, s1, b1[c0 + 1]), 0.f);
    float r2 = fmaxf(fmaf(dn, s2, b1[c0 + 2]), 0.f);
    float r3 = fmaxf(fmaf(dn, s3, b1[c0 + 3]), 0.f);
    float p[NCLS];
#pragma unroll
    for (int c = 0; c < NCLS; ++c)
        p[c] = r0 * w2s[(c0 + 0) * NCLS + c] + r1 * w2s[(c0 + 1) * NCLS + c]
             + r2 * w2s[(c0 + 2) * NCLS + c] + r3 * w2s[(c0 + 3) * NCLS + c];
#pragma unroll
    for (int c = 0; c < NCLS; ++c) {
        p[c] += __shfl_xor(p[c], 1);
        p[c] += __shfl_xor(p[c], 2);
    }
    // static chunk select (no dynamic register-array index)
    float o0, o1, o2, o3;
    if (q == 0)      { o0 = p[0]; o1 = p[1]; o2 = p[2]; o3 = p[3]; }
    else if (q == 1) { o0 = p[4]; o1 = p[5]; o2 = p[6]; o3 = p[7]; }
    else if (q == 2) { o0 = p[8]; o1 = p[9]; o2 = 0.f;  o3 = 0.f;  }
    else             { o0 = 0.f;  o1 = 0.f;  o2 = 0.f;  o3 = 0.f;  }
    float2 st = make_float2(h2f_pack(o0 * dn, o1 * dn), h2f_pack(o2 * dn, o3 * dn));
    ((float2*)ps)[n * 4 + q] = st;
}

// ---------------- layer-2 aggregate + fused log_softmax (fp16 ps in).
// lane q reads chunk q (cols 4q..4q+3); q=3's chunk is all-zero padding and
// its vals are forced to -1e30 -> exp underflows to 0 in the quad sum.
__global__ __launch_bounds__(256) void k_edge2f(const int* __restrict__ row,
                                                const int* __restrict__ srcs,
                                                const float* __restrict__ dinv,
                                                const __half* __restrict__ ps,
                                                const float* __restrict__ b2,
                                                float* __restrict__ out) {
    int t = blockIdx.x * 256 + threadIdx.x;
    if (t >= N_NODES * 4) return;
    int n = t >> 2, q = t & 3;
    const float2* p2 = (const float2*)ps;
    float s0 = 0.f, s1 = 0.f, s2 = 0.f, s3 = 0.f;
    acc4(p2[n * 4 + q], s0, s1, s2, s3);          // self-loop
    int k = row[n], k1 = row[n + 1];
    for (; k + 8 <= k1; k += 8) {
        int a0 = srcs[k],     a1 = srcs[k + 1], a2 = srcs[k + 2], a3 = srcs[k + 3];
        int a4 = srcs[k + 4], a5 = srcs[k + 5], a6 = srcs[k + 6], a7 = srcs[k + 7];
        float2 v0 = p2[a0 * 4 + q], v1 = p2[a1 * 4 + q];
        float2 v2 = p2[a2 * 4 + q], v3 = p2[a3 * 4 + q];
        float2 v4 = p2[a4 * 4 + q], v5 = p2[a5 * 4 + q];
        float2 v6 = p2[a6 * 4 + q], v7 = p2[a7 * 4 + q];
        acc4(v0, s0, s1, s2, s3); acc4(v1, s0, s1, s2, s3);
        acc4(v2, s0, s1, s2, s3); acc4(v3, s0, s1, s2, s3);
        acc4(v4, s0, s1, s2, s3); acc4(v5, s0, s1, s2, s3);
        acc4(v6, s0, s1, s2, s3); acc4(v7, s0, s1, s2, s3);
    }
    if (k < k1) {                                  // masked 8-wide tail
        int sb = srcs[k];
        int idx[8]; float2 vv[8];
#pragma unroll
        for (int j = 0; j < 8; ++j) idx[j] = (k + j < k1) ? srcs[k + j] : sb;
#pragma unroll
        for (int j = 0; j < 8; ++j) vv[j] = p2[idx[j] * 4 + q];
#pragma unroll
        for (int j = 0; j < 8; ++j)
            if (k + j < k1) acc4(vv[j], s0, s1, s2, s3);
    }
    float dn = dinv[n];
    int c0 = q * 4;
    float v0 = (c0 + 0 < NCLS) ? fmaf(dn, s0, b2[c0 + 0]) : -1e30f;
    float v1 = (c0 + 1 < NCLS) ? fmaf(dn, s1, b2[c0 + 1]) : -1e30f;
    float v2 = (c0 + 2 < NCLS) ? fmaf(dn, s2, b2[c0 + 2]) : -1e30f;
    float v3 = (c0 + 3 < NCLS) ? fmaf(dn, s3, b2[c0 + 3]) : -1e30f;
    float m = fmaxf(fmaxf(v0, v1), fmaxf(v2, v3));
    m = fmaxf(m, __shfl_xor(m, 1));
    m = fmaxf(m, __shfl_xor(m, 2));
    float se = __expf(v0 - m) + __expf(v1 - m) + __expf(v2 - m) + __expf(v3 - m);
    se += __shfl_xor(se, 1);
    se += __shfl_xor(se, 2);
    float l = m + __logf(se);
    if (q < 2) {
        float* o = out + n * NCLS + c0;
        o[0] = v0 - l; o[1] = v1 - l; o[2] = v2 - l; o[3] = v3 - l;
    } else if (q == 2) {
        float* o = out + n * NCLS + 8;
        o[0] = v0 - l; o[1] = v1 - l;
    }
}

extern "C" void kernel_launch(void* const* d_in, const int* in_sizes, int n_in,
                              void* d_out, int out_size, void* d_ws, size_t ws_size,
                              hipStream_t stream) {
    const float* x  = (const float*)d_in[0];
    const int*   ei = (const int*)d_in[1];   // [2,E] int32: row0=src, row1=dst
    const float* W1 = (const float*)d_in[2];
    const float* b1 = (const float*)d_in[3];
    const float* W2 = (const float*)d_in[4];
    const float* b2 = (const float*)d_in[5];
    float* out = (float*)d_out;

    int* w = (int*)d_ws;
    float*  dinv  = (float*)w;               // 102400
    int*    row   = w + 102400;              // 102404 -> pad
    int*    bcntp = w + 204816;              // 3136
    int*    bcurp = w + 207952;              // 3136
    int*    boff  = w + 211088;              // 197 -> pad 256
    int*    part  = w + 211344;              // 3.2M packed edges
    int*    srcs  = w + 3411344;             // 3.2M
    __half* h1h   = (__half*)(w + 6611344);  // 100000 x 16 halves (3.2MB)
    __half* ps    = (__half*)(w + 9888144);  // 100000 x 16 halves (3.2MB)

    // CSR build (bucketed, no scattered global atomics)
    k_binit<<<(NB * 16 + 255) / 256, 256, 0, stream>>>(bcntp);
    k_bhist<<<(N_EDGES + 8191) / 8192, 256, 0, stream>>>(ei + N_EDGES, bcntp);
    k_bscan<<<1, 256, 0, stream>>>(bcntp, boff, bcurp, row);
    k_bpart<<<(N_EDGES + EPB - 1) / EPB, 256, 0, stream>>>(ei, bcurp, part);
    k_bucket<<<NB, 256, 0, stream>>>(boff, part, row, dinv, srcs);

    // GCN layers (fp16 gather tables, gemm2 fused into layer-1 aggregate)
    k_gemm1 <<<(N_NODES + 127) / 128, 128, 0, stream>>>(x, W1, dinv, h1h);
    k_edge1f<<<(N_NODES * 4 + 255) / 256, 256, 0, stream>>>(row, srcs, dinv, h1h, b1, W2, ps);
    k_edge2f<<<(N_NODES * 4 + 255) / 256, 256, 0, stream>>>(row, srcs, dinv, ps, b2, out);
}

// Round 2
// 435.617 us; speedup vs baseline: 1.1735x; 1.0431x over previous
//
#include <hip/hip_runtime.h>
#include <hip/hip_fp16.h>

#define N_NODES 100000
#define N_EDGES 3200000
#define F_IN    512
#define HID     16
#define NCLS    10
#define NB      196        // ceil(100000/512) buckets of 512 nodes
#define EPB     4096       // edges per block in k_bpart
#define TK      32         // gemm1 K-chunk

// ---- fp16 pack/unpack helpers (register-safe: no pointer reinterpret of arrays)
union H2F { __half2 h; float f; };
__device__ __forceinline__ float h2f_pack(float a, float b) {
    H2F u; u.h = __floats2half2_rn(a, b); return u.f;
}
__device__ __forceinline__ void h2f_add(float raw, float& a, float& b) {
    H2F u; u.f = raw; float2 v = __half22float2(u.h); a += v.x; b += v.y;
}
__device__ __forceinline__ void acc4(float2 raw, float& a, float& b, float& c, float& d) {
    h2f_add(raw.x, a, b); h2f_add(raw.y, c, d);
}

// ---------------- bucket histogram via LDS (196 buckets, dst>>9), int4 loads
__global__ __launch_bounds__(256) void k_bhist(const int4* __restrict__ dst4,
                                               int* __restrict__ bcntp) {
    __shared__ int h[256];
    int t = threadIdx.x;
    h[t] = 0;
    __syncthreads();
    int base4 = blockIdx.x * 2048;               // 8192 edges = 2048 int4
    int hi4 = min(N_EDGES / 4, base4 + 2048);
    for (int e4 = base4 + t; e4 < hi4; e4 += 256) {
        int4 d = dst4[e4];
        atomicAdd(&h[d.x >> 9], 1);
        atomicAdd(&h[d.y >> 9], 1);
        atomicAdd(&h[d.z >> 9], 1);
        atomicAdd(&h[d.w >> 9], 1);
    }
    __syncthreads();
    if (t < NB) {
        int v = h[t];
        if (v) atomicAdd(&bcntp[t * 16], v);     // padded: 1 counter per 64B line
    }
}

// ---------------- scan bucket counts -> boff[NB+1], init padded cursors
__global__ __launch_bounds__(256) void k_bscan(const int* __restrict__ bcntp,
                                               int* __restrict__ boff,
                                               int* __restrict__ bcurp,
                                               int* __restrict__ row) {
    __shared__ int sh[256];
    int t = threadIdx.x;
    int v = (t < NB) ? bcntp[t * 16] : 0;
    sh[t] = v;
    __syncthreads();
    for (int off = 1; off < 256; off <<= 1) {
        int add = (t >= off) ? sh[t - off] : 0;
        __syncthreads();
        sh[t] += add;
        __syncthreads();
    }
    int excl = sh[t] - v;
    if (t < NB) { boff[t] = excl; bcurp[t * 16] = excl; }
    if (t == 0) { boff[NB] = N_EDGES; row[N_NODES] = N_EDGES; }
}

// ---------------- multisplit partition: edges -> bucket-contiguous packed array
// packed word: ((d & 511) << 17) | s   (s < 2^17, local d < 2^9); int4 loads
__global__ __launch_bounds__(256) void k_bpart(const int* __restrict__ ei,
                                               int* __restrict__ bcurp,
                                               int* __restrict__ part) {
    __shared__ int cnt_sh[256], base_sh[256];
    int t = threadIdx.x;
    cnt_sh[t] = 0;
    __syncthreads();
    const int4* s4 = (const int4*)ei;
    const int4* d4 = (const int4*)(ei + N_EDGES);
    int base4 = blockIdx.x * 1024;               // EPB=4096 edges = 1024 int4
    int pk[16], bk[16], rk[16];
#pragma unroll
    for (int j = 0; j < 4; ++j) {
        int e4 = base4 + j * 256 + t;
        if (e4 < N_EDGES / 4) {
            int4 s = s4[e4], d = d4[e4];
            bk[4 * j + 0] = d.x >> 9; pk[4 * j + 0] = ((d.x & 511) << 17) | s.x;
            bk[4 * j + 1] = d.y >> 9; pk[4 * j + 1] = ((d.y & 511) << 17) | s.y;
            bk[4 * j + 2] = d.z >> 9; pk[4 * j + 2] = ((d.z & 511) << 17) | s.z;
            bk[4 * j + 3] = d.w >> 9; pk[4 * j + 3] = ((d.w & 511) << 17) | s.w;
            rk[4 * j + 0] = atomicAdd(&cnt_sh[bk[4 * j + 0]], 1);
            rk[4 * j + 1] = atomicAdd(&cnt_sh[bk[4 * j + 1]], 1);
            rk[4 * j + 2] = atomicAdd(&cnt_sh[bk[4 * j + 2]], 1);
            rk[4 * j + 3] = atomicAdd(&cnt_sh[bk[4 * j + 3]], 1);
        } else {
            bk[4 * j + 0] = -1; bk[4 * j + 1] = -1;
            bk[4 * j + 2] = -1; bk[4 * j + 3] = -1;
        }
    }
    __syncthreads();
    if (t < NB && cnt_sh[t] > 0)
        base_sh[t] = atomicAdd(&bcurp[t * 16], cnt_sh[t]);
    __syncthreads();
#pragma unroll
    for (int j = 0; j < 16; ++j)
        if (bk[j] >= 0) part[base_sh[bk[j]] + rk[j]] = pk[j];
}

// ---------------- per-bucket: node counts, scan, row/dinv, place srcs (all LDS)
// 1024 threads/block (4 waves/SIMD at 1 block/CU) + 4-way unrolled passes.
__global__ __launch_bounds__(1024) void k_bucket(const int* __restrict__ boff,
                                                 const int* __restrict__ part,
                                                 int* __restrict__ row,
                                                 float* __restrict__ dinv,
                                                 int* __restrict__ srcs) {
    __shared__ int cnt[512], ofs[512];
    int t = threadIdx.x;
    int b = blockIdx.x;
    int e0 = boff[b], e1 = boff[b + 1];
    int nbase = b << 9;
    if (t < 512) cnt[t] = 0;
    __syncthreads();
    for (int e = e0 + t; e < e1; e += 4096) {
        int p0 = part[e];
        int p1 = (e + 1024 < e1) ? part[e + 1024] : -1;
        int p2 = (e + 2048 < e1) ? part[e + 2048] : -1;
        int p3 = (e + 3072 < e1) ? part[e + 3072] : -1;
        atomicAdd(&cnt[p0 >> 17], 1);
        if (p1 >= 0) atomicAdd(&cnt[p1 >> 17], 1);
        if (p2 >= 0) atomicAdd(&cnt[p2 >> 17], 1);
        if (p3 >= 0) atomicAdd(&cnt[p3 >> 17], 1);
    }
    __syncthreads();
    int v = (t < 512) ? cnt[t] : 0;
    if (t < 512) ofs[t] = v;
    __syncthreads();
    for (int off = 1; off < 512; off <<= 1) {
        int add = (t >= off && t < 512) ? ofs[t - off] : 0;
        __syncthreads();
        if (t < 512) ofs[t] += add;
        __syncthreads();
    }
    int excl = (t < 512) ? (ofs[t] - v) : 0;
    __syncthreads();
    if (t < 512) {
        ofs[t] = excl;
        int n = nbase + t;
        if (n < N_NODES) {
            row[n] = e0 + excl;
            dinv[n] = rsqrtf((float)(v + 1));    // +1 self-loop
        }
    }
    __syncthreads();
    for (int e = e0 + t; e < e1; e += 4096) {
        int p0 = part[e];
        int p1 = (e + 1024 < e1) ? part[e + 1024] : -1;
        int p2 = (e + 2048 < e1) ? part[e + 2048] : -1;
        int p3 = (e + 3072 < e1) ? part[e + 3072] : -1;
        int o0 = atomicAdd(&ofs[p0 >> 17], 1);
        srcs[e0 + o0] = p0 & 0x1FFFF;
        if (p1 >= 0) { int o = atomicAdd(&ofs[p1 >> 17], 1); srcs[e0 + o] = p1 & 0x1FFFF; }
        if (p2 >= 0) { int o = atomicAdd(&ofs[p2 >> 17], 1); srcs[e0 + o] = p2 & 0x1FFFF; }
        if (p3 >= 0) { int o = atomicAdd(&ofs[p3 >> 17], 1); srcs[e0 + o] = p3 & 0x1FFFF; }
    }
}

// ---------------- h1h = fp16( dinv[n] * (x @ W1) )   [32B/node row]
__global__ __launch_bounds__(128) void k_gemm1(const float* __restrict__ x,
                                               const float* __restrict__ W1,
                                               const float* __restrict__ dinv,
                                               __half* __restrict__ h1h) {
    __shared__ float xs[128][TK + 1];
    __shared__ float wchunk[TK * 16];      // 512 floats = 128 float4
    const int t = threadIdx.x;
    const int nbase = blockIdx.x * 128;
    const int f4 = t & 7;       // float4 index within chunk row (8 per row)
    const int r0 = t >> 3;      // 0..15; rows r0 + 16p

    float4 pre[8];
#pragma unroll
    for (int p = 0; p < 8; ++p) {
        int n = nbase + r0 + p * 16;
        pre[p] = (n < N_NODES) ? ((const float4*)(x + (size_t)n * F_IN))[f4]
                               : make_float4(0.f, 0.f, 0.f, 0.f);
    }
    float4 wpre = ((const float4*)W1)[t];   // chunk 0's W rows (32x16 = 128 f4)

    float acc[16];
#pragma unroll
    for (int j = 0; j < 16; ++j) acc[j] = 0.f;

    for (int c = 0; c < F_IN; c += TK) {
#pragma unroll
        for (int p = 0; p < 8; ++p) {
            int r = r0 + p * 16;
            xs[r][f4 * 4 + 0] = pre[p].x;
            xs[r][f4 * 4 + 1] = pre[p].y;
            xs[r][f4 * 4 + 2] = pre[p].z;
            xs[r][f4 * 4 + 3] = pre[p].w;
        }
        ((float4*)wchunk)[t] = wpre;
        __syncthreads();
        if (c + TK < F_IN) {
#pragma unroll
            for (int p = 0; p < 8; ++p) {
                int n = nbase + r0 + p * 16;
                pre[p] = (n < N_NODES)
                           ? ((const float4*)(x + (size_t)n * F_IN + c + TK))[f4]
                           : make_float4(0.f, 0.f, 0.f, 0.f);
            }
            wpre = ((const float4*)(W1 + (c + TK) * 16))[t];
        }
#pragma unroll
        for (int k = 0; k < TK; ++k) {
            float xv = xs[t][k];
            const float4* wk = (const float4*)&wchunk[k * 16];
            float4 wa = wk[0], wb = wk[1], wc = wk[2], wd = wk[3];
            acc[0]  = fmaf(xv, wa.x, acc[0]);
            acc[1]  = fmaf(xv, wa.y, acc[1]);
            acc[2]  = fmaf(xv, wa.z, acc[2]);
            acc[3]  = fmaf(xv, wa.w, acc[3]);
            acc[4]  = fmaf(xv, wb.x, acc[4]);
            acc[5]  = fmaf(xv, wb.y, acc[5]);
            acc[6]  = fmaf(xv, wb.z, acc[6]);
            acc[7]  = fmaf(xv, wb.w, acc[7]);
            acc[8]  = fmaf(xv, wc.x, acc[8]);
            acc[9]  = fmaf(xv, wc.y, acc[9]);
            acc[10] = fmaf(xv, wc.z, acc[10]);
            acc[11] = fmaf(xv, wc.w, acc[11]);
            acc[12] = fmaf(xv, wd.x, acc[12]);
            acc[13] = fmaf(xv, wd.y, acc[13]);
            acc[14] = fmaf(xv, wd.z, acc[14]);
            acc[15] = fmaf(xv, wd.w, acc[15]);
        }
        __syncthreads();
    }

    int n = nbase + t;
    if (n < N_NODES) {
        float dn = dinv[n];
        float4 o0 = make_float4(h2f_pack(acc[0]  * dn, acc[1]  * dn),
                                h2f_pack(acc[2]  * dn, acc[3]  * dn),
                                h2f_pack(acc[4]  * dn, acc[5]  * dn),
                                h2f_pack(acc[6]  * dn, acc[7]  * dn));
        float4 o1 = make_float4(h2f_pack(acc[8]  * dn, acc[9]  * dn),
                                h2f_pack(acc[10] * dn, acc[11] * dn),
                                h2f_pack(acc[12] * dn, acc[13] * dn),
                                h2f_pack(acc[14] * dn, acc[15] * dn));
        float4* o = (float4*)(h1h + (size_t)n * 16);
        o[0] = o0; o[1] = o1;
    }
}

// ---------------- layer-1 aggregate + fused gemm2 -> fp16 ps (16 halves/row).
// quad-per-node, 16-deep gather unroll for memory-level parallelism.
__global__ __launch_bounds__(256) void k_edge1f(const int* __restrict__ row,
                                                const int* __restrict__ srcs,
                                                const float* __restrict__ dinv,
                                                const __half* __restrict__ h1h,
                                                const float* __restrict__ b1,
                                                const float* __restrict__ W2,
                                                __half* __restrict__ ps) {
    __shared__ float w2s[HID * NCLS];      // 160 floats
    if (threadIdx.x < HID * NCLS) w2s[threadIdx.x] = W2[threadIdx.x];
    __syncthreads();
    int t = blockIdx.x * 256 + threadIdx.x;
    if (t >= N_NODES * 4) return;
    int n = t >> 2, q = t & 3;
    const float2* h2 = (const float2*)h1h;
    float s0 = 0.f, s1 = 0.f, s2 = 0.f, s3 = 0.f;
    acc4(h2[n * 4 + q], s0, s1, s2, s3);          // self-loop (pre-scaled)
    int k = row[n], k1 = row[n + 1];
    for (; k + 16 <= k1; k += 16) {
        int a[16];
#pragma unroll
        for (int j = 0; j < 16; ++j) a[j] = srcs[k + j];
        float2 v[16];
#pragma unroll
        for (int j = 0; j < 16; ++j) v[j] = h2[a[j] * 4 + q];
#pragma unroll
        for (int j = 0; j < 16; ++j) acc4(v[j], s0, s1, s2, s3);
    }
    if (k < k1) {                                  // masked 16-wide tail
        int sb = srcs[k];
        int a[16];
#pragma unroll
        for (int j = 0; j < 16; ++j) a[j] = (k + j < k1) ? srcs[k + j] : sb;
        float2 v[16];
#pragma unroll
        for (int j = 0; j < 16; ++j) v[j] = h2[a[j] * 4 + q];
#pragma unroll
        for (int j = 0; j < 16; ++j)
            if (k + j < k1) acc4(v[j], s0, s1, s2, s3);
    }
    float dn = dinv[n];
    int c0 = q * 4;
    float r0 = fmaxf(fmaf(dn, s0, b1[c0 + 0]), 0.f);
    float r1 = fmaxf(fmaf(dn, s1, b1[c0 + 1]), 0.f);
    float r2 = fmaxf(fmaf(dn, s2, b1[c0 + 2]), 0.f);
    float r3 = fmaxf(fmaf(dn, s3, b1[c0 + 3]), 0.f);
    float p[NCLS];
#pragma unroll
    for (int c = 0; c < NCLS; ++c)
        p[c] = r0 * w2s[(c0 + 0) * NCLS + c] + r1 * w2s[(c0 + 1) * NCLS + c]
             + r2 * w2s[(c0 + 2) * NCLS + c] + r3 * w2s[(c0 + 3) * NCLS + c];
#pragma unroll
    for (int c = 0; c < NCLS; ++c) {
        p[c] += __shfl_xor(p[c], 1);
        p[c] += __shfl_xor(p[c], 2);
    }
    // static chunk select (no dynamic register-array index)
    float o0, o1, o2, o3;
    if (q == 0)      { o0 = p[0]; o1 = p[1]; o2 = p[2]; o3 = p[3]; }
    else if (q == 1) { o0 = p[4]; o1 = p[5]; o2 = p[6]; o3 = p[7]; }
    else if (q == 2) { o0 = p[8]; o1 = p[9]; o2 = 0.f;  o3 = 0.f;  }
    else             { o0 = 0.f;  o1 = 0.f;  o2 = 0.f;  o3 = 0.f;  }
    float2 st = make_float2(h2f_pack(o0 * dn, o1 * dn), h2f_pack(o2 * dn, o3 * dn));
    ((float2*)ps)[n * 4 + q] = st;
}

// ---------------- layer-2 aggregate + fused log_softmax (fp16 ps in).
__global__ __launch_bounds__(256) void k_edge2f(const int* __restrict__ row,
                                                const int* __restrict__ srcs,
                                                const float* __restrict__ dinv,
                                                const __half* __restrict__ ps,
                                                const float* __restrict__ b2,
                                                float* __restrict__ out) {
    int t = blockIdx.x * 256 + threadIdx.x;
    if (t >= N_NODES * 4) return;
    int n = t >> 2, q = t & 3;
    const float2* p2 = (const float2*)ps;
    float s0 = 0.f, s1 = 0.f, s2 = 0.f, s3 = 0.f;
    acc4(p2[n * 4 + q], s0, s1, s2, s3);          // self-loop
    int k = row[n], k1 = row[n + 1];
    for (; k + 16 <= k1; k += 16) {
        int a[16];
#pragma unroll
        for (int j = 0; j < 16; ++j) a[j] = srcs[k + j];
        float2 v[16];
#pragma unroll
        for (int j = 0; j < 16; ++j) v[j] = p2[a[j] * 4 + q];
#pragma unroll
        for (int j = 0; j < 16; ++j) acc4(v[j], s0, s1, s2, s3);
    }
    if (k < k1) {                                  // masked 16-wide tail
        int sb = srcs[k];
        int a[16];
#pragma unroll
        for (int j = 0; j < 16; ++j) a[j] = (k + j < k1) ? srcs[k + j] : sb;
        float2 v[16];
#pragma unroll
        for (int j = 0; j < 16; ++j) v[j] = p2[a[j] * 4 + q];
#pragma unroll
        for (int j = 0; j < 16; ++j)
            if (k + j < k1) acc4(v[j], s0, s1, s2, s3);
    }
    float dn = dinv[n];
    int c0 = q * 4;
    float v0 = (c0 + 0 < NCLS) ? fmaf(dn, s0, b2[c0 + 0]) : -1e30f;
    float v1 = (c0 + 1 < NCLS) ? fmaf(dn, s1, b2[c0 + 1]) : -1e30f;
    float v2 = (c0 + 2 < NCLS) ? fmaf(dn, s2, b2[c0 + 2]) : -1e30f;
    float v3 = (c0 + 3 < NCLS) ? fmaf(dn, s3, b2[c0 + 3]) : -1e30f;
    float m = fmaxf(fmaxf(v0, v1), fmaxf(v2, v3));
    m = fmaxf(m, __shfl_xor(m, 1));
    m = fmaxf(m, __shfl_xor(m, 2));
    float se = __expf(v0 - m) + __expf(v1 - m) + __expf(v2 - m) + __expf(v3 - m);
    se += __shfl_xor(se, 1);
    se += __shfl_xor(se, 2);
    float l = m + __logf(se);
    if (q < 2) {
        float* o = out + n * NCLS + c0;
        o[0] = v0 - l; o[1] = v1 - l; o[2] = v2 - l; o[3] = v3 - l;
    } else if (q == 2) {
        float* o = out + n * NCLS + 8;
        o[0] = v0 - l; o[1] = v1 - l;
    }
}

extern "C" void kernel_launch(void* const* d_in, const int* in_sizes, int n_in,
                              void* d_out, int out_size, void* d_ws, size_t ws_size,
                              hipStream_t stream) {
    const float* x  = (const float*)d_in[0];
    const int*   ei = (const int*)d_in[1];   // [2,E] int32: row0=src, row1=dst
    const float* W1 = (const float*)d_in[2];
    const float* b1 = (const float*)d_in[3];
    const float* W2 = (const float*)d_in[4];
    const float* b2 = (const float*)d_in[5];
    float* out = (float*)d_out;

    int* w = (int*)d_ws;
    float*  dinv  = (float*)w;               // 102400
    int*    row   = w + 102400;              // 102404 -> pad
    int*    bcntp = w + 204816;              // 3136
    int*    bcurp = w + 207952;              // 3136
    int*    boff  = w + 211088;              // 197 -> pad 256
    int*    part  = w + 211344;              // 3.2M packed edges
    int*    srcs  = w + 3411344;             // 3.2M
    __half* h1h   = (__half*)(w + 6611344);  // 100000 x 16 halves (3.2MB)
    __half* ps    = (__half*)(w + 9888144);  // 100000 x 16 halves (3.2MB)

    // CSR build (bucketed, no scattered global atomics)
    hipMemsetAsync(bcntp, 0, NB * 16 * sizeof(int), stream);
    k_bhist<<<(N_EDGES + 8191) / 8192, 256, 0, stream>>>((const int4*)(ei + N_EDGES), bcntp);
    k_bscan<<<1, 256, 0, stream>>>(bcntp, boff, bcurp, row);
    k_bpart<<<(N_EDGES + EPB - 1) / EPB, 256, 0, stream>>>(ei, bcurp, part);
    k_bucket<<<NB, 1024, 0, stream>>>(boff, part, row, dinv, srcs);

    // GCN layers (fp16 gather tables, gemm2 fused into layer-1 aggregate)
    k_gemm1 <<<(N_NODES + 127) / 128, 128, 0, stream>>>(x, W1, dinv, h1h);
    k_edge1f<<<(N_NODES * 4 + 255) / 256, 256, 0, stream>>>(row, srcs, dinv, h1h, b1, W2, ps);
    k_edge2f<<<(N_NODES * 4 + 255) / 256, 256, 0, stream>>>(row, srcs, dinv, ps, b2, out);
}